// Round 5
// baseline (160.308 us; speedup 1.0000x reference)
//
#include <hip/hip_runtime.h>
#include <math.h>

#define B_    2
#define L_    2048
#define D_    1024
#define H_    16
#define HD_   64
#define HALF_ 128

typedef __attribute__((ext_vector_type(8))) short short8;
typedef __attribute__((ext_vector_type(4))) float f32x4;

// ---- bf16 helpers (bitwise, RNE) -----------------------------------------
__device__ __forceinline__ unsigned short f2bf(float x) {
  unsigned int u = __float_as_uint(x);
  u = (u + 0x7fffu + ((u >> 16) & 1u)) >> 16;
  return (unsigned short)u;
}

__device__ __forceinline__ void async_cp16(const unsigned short* g, unsigned short* l) {
  __builtin_amdgcn_global_load_lds(
      (const __attribute__((address_space(1))) unsigned int*)g,
      (__attribute__((address_space(3))) unsigned int*)l, 16, 0, 0);
}

// ---------------------------------------------------------------------------
// prep: fused (a) x -> bf16 round, (b) w_qkv transpose+round,
//       (c) w_out transpose+round.  (unchanged)
// ---------------------------------------------------------------------------
__device__ __forceinline__ void tr_round32(const float* __restrict__ in,
                                           unsigned short* __restrict__ hi,
                                           int N, int K, int n0, int k0,
                                           float (*t)[33], int tid) {
  {
    const int kl = tid >> 3, nl = (tid & 7) * 4;
    const float4 v = *(const float4*)&in[(size_t)(k0 + kl) * N + n0 + nl];
    t[kl][nl + 0] = v.x; t[kl][nl + 1] = v.y;
    t[kl][nl + 2] = v.z; t[kl][nl + 3] = v.w;
  }
  __syncthreads();
  {
    const int no = tid >> 3, ko = (tid & 7) * 4;
    ushort4 h;
    h.x = f2bf(t[ko + 0][no]);
    h.y = f2bf(t[ko + 1][no]);
    h.z = f2bf(t[ko + 2][no]);
    h.w = f2bf(t[ko + 3][no]);
    *(ushort4*)&hi[(size_t)(n0 + no) * K + k0 + ko] = h;
  }
}

__global__ __launch_bounds__(256) void prep(const float* __restrict__ x,
                                            unsigned short* __restrict__ x_hi,
                                            const float* __restrict__ w_qkv,
                                            unsigned short* __restrict__ wqkvT,
                                            const float* __restrict__ w_out,
                                            unsigned short* __restrict__ woutT) {
  __shared__ float t[32][33];
  const int bx = blockIdx.x, tid = threadIdx.x;
  if (bx < 4096) {
    const int i = (bx * 256 + tid) * 4;
    const float4 a = *(const float4*)&x[i];
    ushort4 h;
    h.x = f2bf(a.x); h.y = f2bf(a.y); h.z = f2bf(a.z); h.w = f2bf(a.w);
    *(ushort4*)&x_hi[i] = h;
  } else if (bx < 7168) {
    const int tb = bx - 4096;  // 96 x 32 tiles
    tr_round32(w_qkv, wqkvT, 3 * D_, D_, (tb % 96) * 32, (tb / 96) * 32, t, tid);
  } else {
    const int tb = bx - 7168;  // 32 x 32 tiles
    tr_round32(w_out, woutT, D_, D_, (tb % 32) * 32, (tb / 32) * 32, t, tid);
  }
}

// ---------------------------------------------------------------------------
// gemm_qkv v3: fused QKV projection, 128x128 tile, BK=32, 32 K-tiles,
// 3-buffer stage-2-ahead pipeline with COUNTED vmcnt (never drains in the
// main loop) + raw s_barrier (1 per K-tile).  Race-freedom: tile j+2 is
// staged into buf (j+2)%3 whose last reads (tile j-1) completed before the
// end-of-(j-1) barrier; vmcnt(4) at tile-j end guarantees tile j+1's 4
// loads landed while j+2's 4 stay in flight.
// Swizzle for 64-B rows: chunk ^= (r>>1)&3  (8 bank-slots / 2-way = free).
// Swapped-operand MFMA + verified 3-way epilogue unchanged from r2.
// Grid 768 blocks (3/CU, LDS 48 KB), bijective XCD swizzle.
// ---------------------------------------------------------------------------
__global__ __launch_bounds__(256, 3) void gemm_qkv(
    const unsigned short* __restrict__ Ah,
    const unsigned short* __restrict__ Bh,
    const float* __restrict__ bias,
    unsigned short* __restrict__ q_hi,
    unsigned short* __restrict__ kT,
    unsigned short* __restrict__ vTile,
    int N, int K) {
  // 3 bufs x 16 KB: per buf A[128][32]bf16 @0 (8 KB) | B[128][32] @8192.
  // v-epilogue bounce reuses as [128][132] ushort (33792 B <= 49152).
  __shared__ char smraw[49152];
  const int tid  = threadIdx.x;
  const int wave = tid >> 6, lane = tid & 63;

  const int lin = blockIdx.y * gridDim.x + blockIdx.x;
  const int swz = (lin & 7) * 96 + (lin >> 3);
  const int n0 = (swz % 24) * 128, m0 = (swz / 24) * 128;

  const int wm = (wave >> 1) * 64, wn = (wave & 1) * 64;
  const int quad = lane >> 4, ln16 = lane & 15;

  // ---- staging: 4 insts/thread/tile (A:2, B:2), each inst = 64 rows ------
  const int srow   = lane >> 2;                          // 0..15 within group
  const int schunk = (lane & 3) ^ ((lane >> 3) & 3);     // involution
  size_t ga[2], gb[2];
  int dA[2], dB[2];
#pragma unroll
  for (int i = 0; i < 2; ++i) {
    const int r = i * 64 + wave * 16 + srow;             // 0..127
    ga[i] = (size_t)(m0 + r) * K + schunk * 8;
    gb[i] = (size_t)(n0 + r) * K + schunk * 8;
    dA[i] = i * 4096 + wave * 1024;
    dB[i] = 8192 + i * 4096 + wave * 1024;
  }

  // ---- ds_read offsets within a buf; swizzle term = (ln16>>1)&3 ----------
  const int sterm = ((ln16 >> 1) & 3);
  int offA[4], offB[4];
#pragma unroll
  for (int t = 0; t < 4; ++t) {
    const int r  = wm + t * 16 + ln16;
    offA[t] = r * 64 + ((quad ^ sterm) * 16);
    const int rn = wn + t * 16 + ln16;
    offB[t] = 8192 + rn * 64 + ((quad ^ sterm) * 16);
  }

  f32x4 acc[4][4] = {};

  // prologue: stage tiles 0,1 (8 insts); wait tile 0 (vmcnt(4))
  {
    char* b0 = smraw;
    char* b1 = smraw + 16384;
#pragma unroll
    for (int i = 0; i < 2; ++i) {
      async_cp16(Ah + ga[i], (unsigned short*)(b0 + dA[i]));
      async_cp16(Bh + gb[i], (unsigned short*)(b0 + dB[i]));
    }
#pragma unroll
    for (int i = 0; i < 2; ++i) {
      async_cp16(Ah + ga[i] + 32, (unsigned short*)(b1 + dA[i]));
      async_cp16(Bh + gb[i] + 32, (unsigned short*)(b1 + dB[i]));
    }
  }
  asm volatile("s_waitcnt vmcnt(4)" ::: "memory");
  __builtin_amdgcn_s_barrier();

  for (int kt = 0; kt < 32; ++kt) {
    if (kt < 30) {  // stage tile kt+2 -> buf (kt+2)%3 (not being read now)
      char* bs = smraw + ((kt + 2) % 3) * 16384;
      const int ko = (kt + 2) * 32;
#pragma unroll
      for (int i = 0; i < 2; ++i) {
        async_cp16(Ah + ga[i] + ko, (unsigned short*)(bs + dA[i]));
        async_cp16(Bh + gb[i] + ko, (unsigned short*)(bs + dB[i]));
      }
    }
    const char* buf = smraw + (kt % 3) * 16384;
    short8 ah[4], bh[4];
#pragma unroll
    for (int t = 0; t < 4; ++t) {
      ah[t] = *(const short8*)(buf + offA[t]);
      bh[t] = *(const short8*)(buf + offB[t]);
    }
#pragma unroll
    for (int t = 0; t < 4; ++t)
#pragma unroll
      for (int u = 0; u < 4; ++u)
        acc[t][u] = __builtin_amdgcn_mfma_f32_16x16x32_bf16(bh[u], ah[t], acc[t][u], 0, 0, 0);
    if (kt < 30) asm volatile("s_waitcnt vmcnt(4)" ::: "memory");
    else         asm volatile("s_waitcnt vmcnt(0)" ::: "memory");
    __builtin_amdgcn_s_barrier();
  }

  // ---- epilogue (verified r2 mapping): m = wm+t*16+ln16 ; n = wn+u*16+quad*4+e
  const int slot = n0 >> 10;
  const int nbase = n0 & 1023;

  if (slot == 0) {
#pragma unroll
    for (int t = 0; t < 4; ++t) {
      const int m = m0 + wm + t * 16 + ln16;
#pragma unroll
      for (int u = 0; u < 4; ++u) {
        const int nl = wn + u * 16 + quad * 4;
        const float4 bq = *(const float4*)&bias[n0 + nl];
        ushort4 h;
        h.x = f2bf(acc[t][u][0] + bq.x);
        h.y = f2bf(acc[t][u][1] + bq.y);
        h.z = f2bf(acc[t][u][2] + bq.z);
        h.w = f2bf(acc[t][u][3] + bq.w);
        *(ushort4*)&q_hi[(size_t)m * 1024 + nbase + nl] = h;
      }
    }
  } else if (slot == 1) {
#pragma unroll
    for (int t = 0; t < 4; ++t) {
      const int tok = m0 + wm + t * 16 + ln16;
      const int bb = tok >> 11, j = tok & 2047;
#pragma unroll
      for (int u = 0; u < 4; ++u) {
        const int nl = wn + u * 16 + quad * 4;
        const float4 bq = *(const float4*)&bias[n0 + nl];
        const int hd = nbase + nl;
        const int hh_ = hd >> 6, dg = (hd & 63) >> 3, di = hd & 7;
        ushort4 h;
        h.x = f2bf(acc[t][u][0] + bq.x);
        h.y = f2bf(acc[t][u][1] + bq.y);
        h.z = f2bf(acc[t][u][2] + bq.z);
        h.w = f2bf(acc[t][u][3] + bq.w);
        const size_t o =
            ((((size_t)bb * 16 + hh_) * 8 + dg) * 2048 + j) * 8 + di;
        *(ushort4*)&kT[o] = h;
      }
    }
  } else {
    unsigned short* lt = (unsigned short*)smraw;
#pragma unroll
    for (int t = 0; t < 4; ++t) {
      const int ml = wm + t * 16 + ln16;
#pragma unroll
      for (int u = 0; u < 4; ++u) {
        const int nl = wn + u * 16 + quad * 4;
        const float4 bq = *(const float4*)&bias[n0 + nl];
        ushort4 h;
        h.x = f2bf(acc[t][u][0] + bq.x);
        h.y = f2bf(acc[t][u][1] + bq.y);
        h.z = f2bf(acc[t][u][2] + bq.z);
        h.w = f2bf(acc[t][u][3] + bq.w);
        *(ushort4*)&lt[ml * 132 + nl] = h;
      }
    }
    __syncthreads();
    const int jg0 = (m0 & 2047) >> 3;
    const int bb = m0 >> 11;
#pragma unroll
    for (int it = 0; it < 8; ++it) {
      const int chunk = it * 256 + tid;
      const int hd = chunk & 127, tokg = chunk >> 7;
      short8 hh;
#pragma unroll
      for (int s = 0; s < 8; ++s)
        hh[s] = (short)lt[(tokg * 8 + s) * 132 + hd];
      const size_t o =
          (((size_t)bb * 256 + jg0 + tokg) * 1024 + nbase + hd) * 8;
      *(short8*)&vTile[o] = hh;
    }
  }
}

// ---------------------------------------------------------------------------
// gemm_out v2: output projection, 128m x 64n, BK=32, 3-buffer counted-vmcnt
// pipeline (same schedule as gemm_qkv: stage j+2, vmcnt(3), 1 barrier/tile).
// 3 x 12 KB LDS.  Swapped-operand epilogue, float4 stores (unchanged).
// ---------------------------------------------------------------------------
__global__ __launch_bounds__(256, 2) void gemm_out(
    const unsigned short* __restrict__ Ah,
    const unsigned short* __restrict__ Bh,
    const float* __restrict__ bias,
    float* __restrict__ C,
    int N, int K) {
  __shared__ char smraw[36864];  // 3 bufs x (A 8 KB | B 4 KB)
  const int tid  = threadIdx.x;
  const int wave = tid >> 6, lane = tid & 63;

  const int lin = blockIdx.y * gridDim.x + blockIdx.x;
  const int swz = (lin & 7) * 64 + (lin >> 3);
  const int n0 = (swz % 16) * 64, m0 = (swz / 16) * 128;

  const int quad = lane >> 4, ln16 = lane & 15;
  const int wm = wave * 32;

  // staging: 3 insts/thread/tile (A:2 over 128 rows, B:1 over 64 rows)
  const int srow   = lane >> 2;
  const int schunk = (lane & 3) ^ ((lane >> 3) & 3);
  size_t ga[2], gbo;
  int dA[2], dBo;
#pragma unroll
  for (int i = 0; i < 2; ++i) {
    const int r = i * 64 + wave * 16 + srow;
    ga[i] = (size_t)(m0 + r) * K + schunk * 8;
    dA[i] = i * 4096 + wave * 1024;
  }
  {
    const int r = wave * 16 + srow;  // 0..63
    gbo = (size_t)(n0 + r) * K + schunk * 8;
    dBo = 8192 + wave * 1024;
  }

  const int sterm = ((ln16 >> 1) & 3);
  int offA[2], offB[4];
#pragma unroll
  for (int t = 0; t < 2; ++t) {
    const int r = wm + t * 16 + ln16;
    offA[t] = r * 64 + ((quad ^ sterm) * 16);
  }
#pragma unroll
  for (int u = 0; u < 4; ++u) {
    const int rn = u * 16 + ln16;
    offB[u] = 8192 + rn * 64 + ((quad ^ sterm) * 16);
  }

  f32x4 acc[2][4] = {};

  // prologue: stage tiles 0,1 (6 insts); wait tile 0 (vmcnt(3))
#pragma unroll
  for (int kt = 0; kt < 2; ++kt) {
    char* bs = smraw + kt * 12288;
    const int ko = kt * 32;
#pragma unroll
    for (int i = 0; i < 2; ++i)
      async_cp16(Ah + ga[i] + ko, (unsigned short*)(bs + dA[i]));
    async_cp16(Bh + gbo + ko, (unsigned short*)(bs + dBo));
  }
  asm volatile("s_waitcnt vmcnt(3)" ::: "memory");
  __builtin_amdgcn_s_barrier();

  for (int kt = 0; kt < 32; ++kt) {
    if (kt < 30) {
      char* bs = smraw + ((kt + 2) % 3) * 12288;
      const int ko = (kt + 2) * 32;
#pragma unroll
      for (int i = 0; i < 2; ++i)
        async_cp16(Ah + ga[i] + ko, (unsigned short*)(bs + dA[i]));
      async_cp16(Bh + gbo + ko, (unsigned short*)(bs + dBo));
    }
    const char* buf = smraw + (kt % 3) * 12288;
    short8 ah[2], bh[4];
#pragma unroll
    for (int t = 0; t < 2; ++t) ah[t] = *(const short8*)(buf + offA[t]);
#pragma unroll
    for (int u = 0; u < 4; ++u) bh[u] = *(const short8*)(buf + offB[u]);
#pragma unroll
    for (int t = 0; t < 2; ++t)
#pragma unroll
      for (int u = 0; u < 4; ++u)
        acc[t][u] = __builtin_amdgcn_mfma_f32_16x16x32_bf16(bh[u], ah[t], acc[t][u], 0, 0, 0);
    if (kt < 30) asm volatile("s_waitcnt vmcnt(3)" ::: "memory");
    else         asm volatile("s_waitcnt vmcnt(0)" ::: "memory");
    __builtin_amdgcn_s_barrier();
  }

#pragma unroll
  for (int t = 0; t < 2; ++t) {
    const int m = m0 + wm + t * 16 + ln16;
#pragma unroll
    for (int u = 0; u < 4; ++u) {
      const int n = n0 + u * 16 + quad * 4;
      const float4 bq = *(const float4*)&bias[n];
      float4 o;
      o.x = acc[t][u][0] + bq.x;
      o.y = acc[t][u][1] + bq.y;
      o.z = acc[t][u][2] + bq.z;
      o.w = acc[t][u][3] + bq.w;
      *(float4*)&C[(size_t)m * N + n] = o;
    }
  }
}

// ---------------------------------------------------------------------------
// attn_mfma v2 (unchanged from r4): swapped-operand QK^T, in-register P,
// TQ=64, single barrier.
// ---------------------------------------------------------------------------
__global__ __launch_bounds__(256) void attn_mfma(
    const unsigned short* __restrict__ q_hi,
    const unsigned short* __restrict__ kT,
    const unsigned short* __restrict__ vTile,
    unsigned short* __restrict__ attn_h) {
  __shared__ float ob[64 * 68];  // 17408 B

  const int b   = blockIdx.z;
  const int h   = blockIdx.y;
  const int i0  = blockIdx.x * 64;
  const int tid = threadIdx.x;
  const int mt  = tid >> 6, lane = tid & 63;
  const int quad = lane >> 4, ln16 = lane & 15;
  const int jlo = i0 - HALF_;

  const size_t qbase =
      (size_t)(b * L_ + i0 + mt * 16 + ln16) * 1024 + h * 64 + quad * 8;
  const short8 qh0 = *(const short8*)&q_hi[qbase];
  const short8 qh1 = *(const short8*)&q_hi[qbase + 32];

  const size_t kb0 = (((size_t)b * 16 + h) * 8 + quad) * 2048 * 8;
  const size_t kb1 = (((size_t)b * 16 + h) * 8 + quad + 4) * 2048 * 8;

  const int iabs = i0 + mt * 16 + ln16;

  f32x4 o[4] = {};
  float s = 0.f;

#pragma unroll
  for (int c = 0; c < 10; ++c) {
    const int base = jlo + c * 32;

    const int j0c = min(max(base + ln16, 0), L_ - 1);
    const int j1c = min(max(base + 16 + ln16, 0), L_ - 1);
    const short8 k00 = *(const short8*)&kT[kb0 + (size_t)j0c * 8];
    const short8 k01 = *(const short8*)&kT[kb1 + (size_t)j0c * 8];
    const short8 k10 = *(const short8*)&kT[kb0 + (size_t)j1c * 8];
    const short8 k11 = *(const short8*)&kT[kb1 + (size_t)j1c * 8];

    const int jv = min(max(base + quad * 8, 0), L_ - 8);
    const size_t vgb = ((size_t)b * 256 + (jv >> 3)) * 1024 + h * 64;
    short8 vh[4];
#pragma unroll
    for (int t = 0; t < 4; ++t)
      vh[t] = *(const short8*)&vTile[(vgb + t * 16 + ln16) * 8];

    f32x4 a0 = {}, a1 = {};
    a0 = __builtin_amdgcn_mfma_f32_16x16x32_bf16(k00, qh0, a0, 0, 0, 0);
    a0 = __builtin_amdgcn_mfma_f32_16x16x32_bf16(k01, qh1, a0, 0, 0, 0);
    a1 = __builtin_amdgcn_mfma_f32_16x16x32_bf16(k10, qh0, a1, 0, 0, 0);
    a1 = __builtin_amdgcn_mfma_f32_16x16x32_bf16(k11, qh1, a1, 0, 0, 0);

    unsigned int pk00, pk01, pk10, pk11;
    {
      float ev[4];
#pragma unroll
      for (int e = 0; e < 4; ++e) {
        const int jabs = base + quad * 4 + e;
        const bool ok = (jabs >= 0) && (jabs < L_) && (abs(iabs - jabs) <= HALF_);
        ev[e] = ok ? __expf(a0[e] * 0.125f) : 0.f;
        s += ev[e];
      }
      pk00 = (unsigned)f2bf(ev[0]) | ((unsigned)f2bf(ev[1]) << 16);
      pk01 = (unsigned)f2bf(ev[2]) | ((unsigned)f2bf(ev[3]) << 16);
    }
    {
      float ev[4];
#pragma unroll
      for (int e = 0; e < 4; ++e) {
        const int jabs = base + 16 + quad * 4 + e;
        const bool ok = (jabs >= 0) && (jabs < L_) && (abs(iabs - jabs) <= HALF_);
        ev[e] = ok ? __expf(a1[e] * 0.125f) : 0.f;
        s += ev[e];
      }
      pk10 = (unsigned)f2bf(ev[0]) | ((unsigned)f2bf(ev[1]) << 16);
      pk11 = (unsigned)f2bf(ev[2]) | ((unsigned)f2bf(ev[3]) << 16);
    }

    const int src0 = ((quad & 1) * 2) * 16 + ln16;
    const int src1 = src0 + 16;
    const unsigned a0w = (unsigned)__shfl((int)pk00, src0);
    const unsigned b0w = (unsigned)__shfl((int)pk10, src0);
    const unsigned a1w = (unsigned)__shfl((int)pk01, src0);
    const unsigned b1w = (unsigned)__shfl((int)pk11, src0);
    const unsigned a2w = (unsigned)__shfl((int)pk00, src1);
    const unsigned b2w = (unsigned)__shfl((int)pk10, src1);
    const unsigned a3w = (unsigned)__shfl((int)pk01, src1);
    const unsigned b3w = (unsigned)__shfl((int)pk11, src1);
    int4 wv;
    wv.x = (int)((quad < 2) ? a0w : b0w);
    wv.y = (int)((quad < 2) ? a1w : b1w);
    wv.z = (int)((quad < 2) ? a2w : b2w);
    wv.w = (int)((quad < 2) ? a3w : b3w);
    const short8 pf = *(const short8*)&wv;

#pragma unroll
    for (int t = 0; t < 4; ++t)
      o[t] = __builtin_amdgcn_mfma_f32_16x16x32_bf16(pf, vh[t], o[t], 0, 0, 0);
  }

  s += __shfl_xor(s, 16);
  s += __shfl_xor(s, 32);
  float rinv[4];
#pragma unroll
  for (int e = 0; e < 4; ++e)
    rinv[e] = 1.f / __shfl(s, quad * 4 + e);

#pragma unroll
  for (int t = 0; t < 4; ++t)
#pragma unroll
    for (int e = 0; e < 4; ++e)
      ob[(mt * 16 + quad * 4 + e) * 68 + t * 16 + ln16] = o[t][e] * rinv[e];
  __syncthreads();
#pragma unroll
  for (int pass = 0; pass < 2; ++pass) {
    const int rr = pass * 32 + (tid >> 3), ck = tid & 7;
    const float* rp = &ob[rr * 68 + ck * 8];
    const float4 f0 = *(const float4*)&rp[0];
    const float4 f1 = *(const float4*)&rp[4];
    short8 hh;
    hh[0] = (short)f2bf(f0.x); hh[1] = (short)f2bf(f0.y);
    hh[2] = (short)f2bf(f0.z); hh[3] = (short)f2bf(f0.w);
    hh[4] = (short)f2bf(f1.x); hh[5] = (short)f2bf(f1.y);
    hh[6] = (short)f2bf(f1.z); hh[7] = (short)f2bf(f1.w);
    const size_t oo = ((size_t)(b * L_ + i0 + rr)) * 1024 + h * 64 + ck * 8;
    *(short8*)&attn_h[oo] = hh;
  }
}

// ---------------------------------------------------------------------------
extern "C" void kernel_launch(void* const* d_in, const int* in_sizes, int n_in,
                              void* d_out, int out_size, void* d_ws, size_t ws_size,
                              hipStream_t stream) {
  const float* x     = (const float*)d_in[0];
  const float* w_qkv = (const float*)d_in[1];
  const float* b_qkv = (const float*)d_in[2];
  const float* w_out = (const float*)d_in[3];
  const float* b_out = (const float*)d_in[4];
  float* out = (float*)d_out;

  const int M = B_ * L_;  // 4096

  // workspace layout (bytes), total 48 MiB:
  //   x_hi @0 (8MiB)        [dead after QKV gemm; attn_h aliases it]
  //   wqkvT @16MiB (6MiB)
  //   woutT @22MiB (2MiB)
  //   q_hi  @24MiB (8MiB)   [B*L, 1024]
  //   kT    @32MiB (8MiB)   [b][h][dg8][j2048][8d]
  //   vTile @40MiB (8MiB)   [b][jg256][d1024][8j]
  char* ws = (char*)d_ws;
  unsigned short* x_hi    = (unsigned short*)(ws + 0);
  unsigned short* wqkvT   = (unsigned short*)(ws + 16777216);
  unsigned short* woutT   = (unsigned short*)(ws + 23068672);
  unsigned short* q_hi    = (unsigned short*)(ws + 25165824);
  unsigned short* kT      = (unsigned short*)(ws + 33554432);
  unsigned short* vTile   = (unsigned short*)(ws + 41943040);
  unsigned short* attn_hi = (unsigned short*)(ws + 0);

  // 1) fused prep: x round + both weight transposes
  prep<<<8192, 256, 0, stream>>>(x, x_hi, w_qkv, wqkvT, w_out, woutT);
  // 2) fused QKV projection (3-buf counted-vmcnt pipeline) -> q_hi/kT/vTile
  {
    dim3 g(3072 / 128, M / 128);  // 768 blocks = 3/CU
    gemm_qkv<<<g, 256, 0, stream>>>(x_hi, wqkvT, b_qkv, q_hi, kT, vTile,
                                    3072, D_);
  }
  // 3) banded attention v2 (TQ=64, in-register P) -> attn_h bf16
  {
    dim3 g(L_ / 64, H_, B_);  // 1024 blocks
    attn_mfma<<<g, 256, 0, stream>>>(q_hi, kT, vTile, attn_hi);
  }
  // 4) output projection (3-buf counted-vmcnt pipeline) -> fp32 d_out
  {
    dim3 g(D_ / 64, M / 128);  // 512 blocks
    gemm_out<<<g, 256, 0, stream>>>(attn_hi, woutT, b_out, out, D_, D_);
  }
}

// Round 6
// 156.629 us; speedup vs baseline: 1.0235x; 1.0235x over previous
//
#include <hip/hip_runtime.h>
#include <math.h>

#define B_    2
#define L_    2048
#define D_    1024
#define H_    16
#define HD_   64
#define HALF_ 128

typedef __attribute__((ext_vector_type(8))) short short8;
typedef __attribute__((ext_vector_type(4))) float f32x4;

// ---- bf16 helpers (bitwise, RNE) -----------------------------------------
__device__ __forceinline__ unsigned short f2bf(float x) {
  unsigned int u = __float_as_uint(x);
  u = (u + 0x7fffu + ((u >> 16) & 1u)) >> 16;
  return (unsigned short)u;
}

__device__ __forceinline__ void async_cp16(const unsigned short* g, unsigned short* l) {
  __builtin_amdgcn_global_load_lds(
      (const __attribute__((address_space(1))) unsigned int*)g,
      (__attribute__((address_space(3))) unsigned int*)l, 16, 0, 0);
}

// ---------------------------------------------------------------------------
// prep: fused (a) x -> bf16 round, (b) w_qkv transpose+round,
//       (c) w_out transpose+round.  (unchanged)
// ---------------------------------------------------------------------------
__device__ __forceinline__ void tr_round32(const float* __restrict__ in,
                                           unsigned short* __restrict__ hi,
                                           int N, int K, int n0, int k0,
                                           float (*t)[33], int tid) {
  {
    const int kl = tid >> 3, nl = (tid & 7) * 4;
    const float4 v = *(const float4*)&in[(size_t)(k0 + kl) * N + n0 + nl];
    t[kl][nl + 0] = v.x; t[kl][nl + 1] = v.y;
    t[kl][nl + 2] = v.z; t[kl][nl + 3] = v.w;
  }
  __syncthreads();
  {
    const int no = tid >> 3, ko = (tid & 7) * 4;
    ushort4 h;
    h.x = f2bf(t[ko + 0][no]);
    h.y = f2bf(t[ko + 1][no]);
    h.z = f2bf(t[ko + 2][no]);
    h.w = f2bf(t[ko + 3][no]);
    *(ushort4*)&hi[(size_t)(n0 + no) * K + k0 + ko] = h;
  }
}

__global__ __launch_bounds__(256) void prep(const float* __restrict__ x,
                                            unsigned short* __restrict__ x_hi,
                                            const float* __restrict__ w_qkv,
                                            unsigned short* __restrict__ wqkvT,
                                            const float* __restrict__ w_out,
                                            unsigned short* __restrict__ woutT) {
  __shared__ float t[32][33];
  const int bx = blockIdx.x, tid = threadIdx.x;
  if (bx < 4096) {
    const int i = (bx * 256 + tid) * 4;
    const float4 a = *(const float4*)&x[i];
    ushort4 h;
    h.x = f2bf(a.x); h.y = f2bf(a.y); h.z = f2bf(a.z); h.w = f2bf(a.w);
    *(ushort4*)&x_hi[i] = h;
  } else if (bx < 7168) {
    const int tb = bx - 4096;  // 96 x 32 tiles
    tr_round32(w_qkv, wqkvT, 3 * D_, D_, (tb % 96) * 32, (tb / 96) * 32, t, tid);
  } else {
    const int tb = bx - 7168;  // 32 x 32 tiles
    tr_round32(w_out, woutT, D_, D_, (tb % 32) * 32, (tb / 32) * 32, t, tid);
  }
}

// ---------------------------------------------------------------------------
// gemm_qkv (r4 version, measured best): 128x128 tile, BK=64, 32 KB LDS,
// chunk^=(r&7) swizzle, swapped-operand MFMA, 3-way epilogue.
// Grid 768 blocks (3/CU), bijective XCD swizzle.
// ---------------------------------------------------------------------------
__global__ __launch_bounds__(256, 3) void gemm_qkv(
    const unsigned short* __restrict__ Ah,
    const unsigned short* __restrict__ Bh,
    const float* __restrict__ bias,
    unsigned short* __restrict__ q_hi,
    unsigned short* __restrict__ kT,
    unsigned short* __restrict__ vTile,
    int N, int K) {
  __shared__ char smraw[33792];
  const int tid  = threadIdx.x;
  const int wave = tid >> 6, lane = tid & 63;

  const int lin = blockIdx.y * gridDim.x + blockIdx.x;
  const int swz = (lin & 7) * 96 + (lin >> 3);
  const int n0 = (swz % 24) * 128, m0 = (swz / 24) * 128;

  const int wm = (wave >> 1) * 64, wn = (wave & 1) * 64;
  const int quad = lane >> 4, ln16 = lane & 15;

  const bool isA = wave < 2;
  const unsigned short* src = isA ? Ah : Bh;
  const int baserow = isA ? m0 : n0;
  const int instbase = (wave & 1) * 8;
  const int dbase = (isA ? 0 : 16384) + instbase * 1024;
  size_t goff[8];
#pragma unroll
  for (int i = 0; i < 8; ++i) {
    const int r = (instbase + i) * 8 + (lane >> 3);
    const int c = (lane & 7) ^ (r & 7);
    goff[i] = (size_t)(baserow + r) * K + c * 8;
  }

  int offA[4], offB[4];
#pragma unroll
  for (int t = 0; t < 4; ++t) {
    const int r = wm + t * 16 + ln16;
    offA[t] = r * 128 + ((quad ^ (r & 7)) * 16);
    const int rn = wn + t * 16 + ln16;
    offB[t] = 16384 + rn * 128 + ((quad ^ (rn & 7)) * 16);
  }

  f32x4 acc[4][4] = {};
  const char* smb = (const char*)smraw;

  for (int k0 = 0; k0 < K; k0 += 64) {
#pragma unroll
    for (int i = 0; i < 8; ++i)
      async_cp16(src + goff[i] + k0,
                 (unsigned short*)(smraw + dbase + i * 1024));
    __syncthreads();

    {
      short8 ah[4], bh[4];
#pragma unroll
      for (int t = 0; t < 4; ++t) {
        ah[t] = *(const short8*)(smb + offA[t]);
        bh[t] = *(const short8*)(smb + offB[t]);
      }
#pragma unroll
      for (int t = 0; t < 4; ++t)
#pragma unroll
        for (int u = 0; u < 4; ++u)
          acc[t][u] = __builtin_amdgcn_mfma_f32_16x16x32_bf16(bh[u], ah[t], acc[t][u], 0, 0, 0);
    }
    {
      short8 ah[4], bh[4];
#pragma unroll
      for (int t = 0; t < 4; ++t) {
        ah[t] = *(const short8*)(smb + (offA[t] ^ 64));
        bh[t] = *(const short8*)(smb + (offB[t] ^ 64));
      }
#pragma unroll
      for (int t = 0; t < 4; ++t)
#pragma unroll
        for (int u = 0; u < 4; ++u)
          acc[t][u] = __builtin_amdgcn_mfma_f32_16x16x32_bf16(bh[u], ah[t], acc[t][u], 0, 0, 0);
    }
    __syncthreads();
  }

  const int slot = n0 >> 10;
  const int nbase = n0 & 1023;

  if (slot == 0) {
#pragma unroll
    for (int t = 0; t < 4; ++t) {
      const int m = m0 + wm + t * 16 + ln16;
#pragma unroll
      for (int u = 0; u < 4; ++u) {
        const int nl = wn + u * 16 + quad * 4;
        const float4 bq = *(const float4*)&bias[n0 + nl];
        ushort4 h;
        h.x = f2bf(acc[t][u][0] + bq.x);
        h.y = f2bf(acc[t][u][1] + bq.y);
        h.z = f2bf(acc[t][u][2] + bq.z);
        h.w = f2bf(acc[t][u][3] + bq.w);
        *(ushort4*)&q_hi[(size_t)m * 1024 + nbase + nl] = h;
      }
    }
  } else if (slot == 1) {
#pragma unroll
    for (int t = 0; t < 4; ++t) {
      const int tok = m0 + wm + t * 16 + ln16;
      const int bb = tok >> 11, j = tok & 2047;
#pragma unroll
      for (int u = 0; u < 4; ++u) {
        const int nl = wn + u * 16 + quad * 4;
        const float4 bq = *(const float4*)&bias[n0 + nl];
        const int hd = nbase + nl;
        const int hh_ = hd >> 6, dg = (hd & 63) >> 3, di = hd & 7;
        ushort4 h;
        h.x = f2bf(acc[t][u][0] + bq.x);
        h.y = f2bf(acc[t][u][1] + bq.y);
        h.z = f2bf(acc[t][u][2] + bq.z);
        h.w = f2bf(acc[t][u][3] + bq.w);
        const size_t o =
            ((((size_t)bb * 16 + hh_) * 8 + dg) * 2048 + j) * 8 + di;
        *(ushort4*)&kT[o] = h;
      }
    }
  } else {
    unsigned short* lt = (unsigned short*)smraw;
#pragma unroll
    for (int t = 0; t < 4; ++t) {
      const int ml = wm + t * 16 + ln16;
#pragma unroll
      for (int u = 0; u < 4; ++u) {
        const int nl = wn + u * 16 + quad * 4;
        const float4 bq = *(const float4*)&bias[n0 + nl];
        ushort4 h;
        h.x = f2bf(acc[t][u][0] + bq.x);
        h.y = f2bf(acc[t][u][1] + bq.y);
        h.z = f2bf(acc[t][u][2] + bq.z);
        h.w = f2bf(acc[t][u][3] + bq.w);
        *(ushort4*)&lt[ml * 132 + nl] = h;
      }
    }
    __syncthreads();
    const int jg0 = (m0 & 2047) >> 3;
    const int bb = m0 >> 11;
#pragma unroll
    for (int it = 0; it < 8; ++it) {
      const int chunk = it * 256 + tid;
      const int hd = chunk & 127, tokg = chunk >> 7;
      short8 hh;
#pragma unroll
      for (int s = 0; s < 8; ++s)
        hh[s] = (short)lt[(tokg * 8 + s) * 132 + hd];
      const size_t o =
          (((size_t)bb * 256 + jg0 + tokg) * 1024 + nbase + hd) * 8;
      *(short8*)&vTile[o] = hh;
    }
  }
}

// ---------------------------------------------------------------------------
// gemm_out (r4 version, measured best): 128m x 64n, BK=64, 24 KB LDS,
// swapped-operand epilogue, float4 stores.
// ---------------------------------------------------------------------------
__global__ __launch_bounds__(256, 2) void gemm_out(
    const unsigned short* __restrict__ Ah,
    const unsigned short* __restrict__ Bh,
    const float* __restrict__ bias,
    float* __restrict__ C,
    int N, int K) {
  __shared__ char smraw[24576];
  const int tid  = threadIdx.x;
  const int wave = tid >> 6, lane = tid & 63;

  const int lin = blockIdx.y * gridDim.x + blockIdx.x;
  const int swz = (lin & 7) * 64 + (lin >> 3);
  const int n0 = (swz % 16) * 64, m0 = (swz / 16) * 128;

  const int quad = lane >> 4, ln16 = lane & 15;
  const int wm = wave * 32;

  const unsigned short* sptr[6];
  int dstoff[6];
#pragma unroll
  for (int s = 0; s < 6; ++s) {
    const int g = wave * 6 + s;
    const bool isA = g < 16;
    const unsigned short* base = isA ? Ah : Bh;
    const int r0 = isA ? g * 8 : (g - 16) * 8;
    const int r = r0 + (lane >> 3);
    const int c = (lane & 7) ^ (r & 7);
    sptr[s] = base + (size_t)((isA ? m0 : n0) + r) * K + c * 8;
    dstoff[s] = isA ? g * 1024 : 16384 + (g - 16) * 1024;
  }

  int offA[2], offB[4];
#pragma unroll
  for (int t = 0; t < 2; ++t) {
    const int r = wm + t * 16 + ln16;
    offA[t] = r * 128 + ((quad ^ (r & 7)) * 16);
  }
#pragma unroll
  for (int u = 0; u < 4; ++u) {
    const int rn = u * 16 + ln16;
    offB[u] = 16384 + rn * 128 + ((quad ^ (rn & 7)) * 16);
  }

  f32x4 acc[2][4] = {};
  const char* smb = (const char*)smraw;

  for (int k0 = 0; k0 < K; k0 += 64) {
#pragma unroll
    for (int s = 0; s < 6; ++s)
      async_cp16(sptr[s] + k0, (unsigned short*)(smraw + dstoff[s]));
    __syncthreads();

    {
      short8 ah[2], bh[4];
#pragma unroll
      for (int t = 0; t < 2; ++t) ah[t] = *(const short8*)(smb + offA[t]);
#pragma unroll
      for (int u = 0; u < 4; ++u) bh[u] = *(const short8*)(smb + offB[u]);
#pragma unroll
      for (int t = 0; t < 2; ++t)
#pragma unroll
        for (int u = 0; u < 4; ++u)
          acc[t][u] = __builtin_amdgcn_mfma_f32_16x16x32_bf16(bh[u], ah[t], acc[t][u], 0, 0, 0);
    }
    {
      short8 ah[2], bh[4];
#pragma unroll
      for (int t = 0; t < 2; ++t) ah[t] = *(const short8*)(smb + (offA[t] ^ 64));
#pragma unroll
      for (int u = 0; u < 4; ++u) bh[u] = *(const short8*)(smb + (offB[u] ^ 64));
#pragma unroll
      for (int t = 0; t < 2; ++t)
#pragma unroll
        for (int u = 0; u < 4; ++u)
          acc[t][u] = __builtin_amdgcn_mfma_f32_16x16x32_bf16(bh[u], ah[t], acc[t][u], 0, 0, 0);
    }
    __syncthreads();
  }

#pragma unroll
  for (int t = 0; t < 2; ++t) {
    const int m = m0 + wm + t * 16 + ln16;
#pragma unroll
    for (int u = 0; u < 4; ++u) {
      const int n = n0 + u * 16 + quad * 4;
      const float4 bq = *(const float4*)&bias[n];
      float4 o;
      o.x = acc[t][u][0] + bq.x;
      o.y = acc[t][u][1] + bq.y;
      o.z = acc[t][u][2] + bq.z;
      o.w = acc[t][u][3] + bq.w;
      *(float4*)&C[(size_t)m * N + n] = o;
    }
  }
}

// ---------------------------------------------------------------------------
// attn_mfma v3: v2 structure (swapped QK^T, in-register P, TQ=64) plus:
//  - XCD-pinned block remap: all 32 i0-blocks of one (b,h) land on one XCD
//    (512 KB K/V window becomes XCD-L2-resident; kills cross-XCD refetch).
//  - 2-deep register prefetch of K/V (issue c+1 loads before computing c).
//  - s_setprio(1) around MFMA clusters.
// ---------------------------------------------------------------------------
__global__ __launch_bounds__(256) void attn_mfma(
    const unsigned short* __restrict__ q_hi,
    const unsigned short* __restrict__ kT,
    const unsigned short* __restrict__ vTile,
    unsigned short* __restrict__ attn_h) {
  __shared__ float ob[64 * 68];  // 17408 B

  const int tid = threadIdx.x;
  const int mt  = tid >> 6, lane = tid & 63;
  const int quad = lane >> 4, ln16 = lane & 15;

  // XCD-pinned bijective remap of 1024 blocks -> (b, h, i0):
  //   xcd = lin & 7 owns pairs [xcd*4, xcd*4+4); i0 walks fastest.
  const int lin  = blockIdx.x + gridDim.x * (blockIdx.y + gridDim.y * blockIdx.z);
  const int xcd  = lin & 7, idx = lin >> 3;          // idx 0..127
  const int pair = xcd * 4 + (idx >> 5);             // 0..31
  const int i0   = (idx & 31) * 64;
  const int b    = pair >> 4, h = pair & 15;
  const int jlo  = i0 - HALF_;

  // Q as B-frag: lane holds Q[q = mt*16+ln16][d = quad*8 + i (+32)]
  const size_t qbase =
      (size_t)(b * L_ + i0 + mt * 16 + ln16) * 1024 + h * 64 + quad * 8;
  const short8 qh0 = *(const short8*)&q_hi[qbase];
  const short8 qh1 = *(const short8*)&q_hi[qbase + 32];

  const size_t kb0 = (((size_t)b * 16 + h) * 8 + quad) * 2048 * 8;
  const size_t kb1 = (((size_t)b * 16 + h) * 8 + quad + 4) * 2048 * 8;

  const int iabs = i0 + mt * 16 + ln16;

  f32x4 o[4] = {};
  float s = 0.f;

  short8 kf[2][4], vf[2][4];
  // preload slab c = 0
  {
    const int base = jlo;
    const int j0c = min(max(base + ln16, 0), L_ - 1);
    const int j1c = min(max(base + 16 + ln16, 0), L_ - 1);
    kf[0][0] = *(const short8*)&kT[kb0 + (size_t)j0c * 8];
    kf[0][1] = *(const short8*)&kT[kb1 + (size_t)j0c * 8];
    kf[0][2] = *(const short8*)&kT[kb0 + (size_t)j1c * 8];
    kf[0][3] = *(const short8*)&kT[kb1 + (size_t)j1c * 8];
    const int jv = min(max(base + quad * 8, 0), L_ - 8);
    const size_t vgb = ((size_t)b * 256 + (jv >> 3)) * 1024 + h * 64;
#pragma unroll
    for (int t = 0; t < 4; ++t)
      vf[0][t] = *(const short8*)&vTile[(vgb + t * 16 + ln16) * 8];
  }

#pragma unroll
  for (int c = 0; c < 10; ++c) {
    const int cur = c & 1, nxt = cur ^ 1;

    // ---- issue next slab's loads (stay in flight under this slab's math) -
    if (c < 9) {
      const int nb = jlo + (c + 1) * 32;
      const int j0c = min(max(nb + ln16, 0), L_ - 1);
      const int j1c = min(max(nb + 16 + ln16, 0), L_ - 1);
      kf[nxt][0] = *(const short8*)&kT[kb0 + (size_t)j0c * 8];
      kf[nxt][1] = *(const short8*)&kT[kb1 + (size_t)j0c * 8];
      kf[nxt][2] = *(const short8*)&kT[kb0 + (size_t)j1c * 8];
      kf[nxt][3] = *(const short8*)&kT[kb1 + (size_t)j1c * 8];
      const int jv = min(max(nb + quad * 8, 0), L_ - 8);
      const size_t vgb = ((size_t)b * 256 + (jv >> 3)) * 1024 + h * 64;
#pragma unroll
      for (int t = 0; t < 4; ++t)
        vf[nxt][t] = *(const short8*)&vTile[(vgb + t * 16 + ln16) * 8];
    }

    const int base = jlo + c * 32;

    // ---- swapped QK^T: D[j-off = quad*4+e][q = ln16] ---------------------
    f32x4 a0 = {}, a1 = {};
    __builtin_amdgcn_s_setprio(1);
    a0 = __builtin_amdgcn_mfma_f32_16x16x32_bf16(kf[cur][0], qh0, a0, 0, 0, 0);
    a0 = __builtin_amdgcn_mfma_f32_16x16x32_bf16(kf[cur][1], qh1, a0, 0, 0, 0);
    a1 = __builtin_amdgcn_mfma_f32_16x16x32_bf16(kf[cur][2], qh0, a1, 0, 0, 0);
    a1 = __builtin_amdgcn_mfma_f32_16x16x32_bf16(kf[cur][3], qh1, a1, 0, 0, 0);
    __builtin_amdgcn_s_setprio(0);

    // ---- mask + exp + bf16 pack ------------------------------------------
    unsigned int pk00, pk01, pk10, pk11;
    {
      float ev[4];
#pragma unroll
      for (int e = 0; e < 4; ++e) {
        const int jabs = base + quad * 4 + e;
        const bool ok = (jabs >= 0) && (jabs < L_) && (abs(iabs - jabs) <= HALF_);
        ev[e] = ok ? __expf(a0[e] * 0.125f) : 0.f;
        s += ev[e];
      }
      pk00 = (unsigned)f2bf(ev[0]) | ((unsigned)f2bf(ev[1]) << 16);
      pk01 = (unsigned)f2bf(ev[2]) | ((unsigned)f2bf(ev[3]) << 16);
    }
    {
      float ev[4];
#pragma unroll
      for (int e = 0; e < 4; ++e) {
        const int jabs = base + 16 + quad * 4 + e;
        const bool ok = (jabs >= 0) && (jabs < L_) && (abs(iabs - jabs) <= HALF_);
        ev[e] = ok ? __expf(a1[e] * 0.125f) : 0.f;
        s += ev[e];
      }
      pk10 = (unsigned)f2bf(ev[0]) | ((unsigned)f2bf(ev[1]) << 16);
      pk11 = (unsigned)f2bf(ev[2]) | ((unsigned)f2bf(ev[3]) << 16);
    }

    // ---- assemble P A-frag: pf[i] = P[q=ln16][base + quad*8 + i] ---------
    const int src0 = ((quad & 1) * 2) * 16 + ln16;
    const int src1 = src0 + 16;
    const unsigned a0w = (unsigned)__shfl((int)pk00, src0);
    const unsigned b0w = (unsigned)__shfl((int)pk10, src0);
    const unsigned a1w = (unsigned)__shfl((int)pk01, src0);
    const unsigned b1w = (unsigned)__shfl((int)pk11, src0);
    const unsigned a2w = (unsigned)__shfl((int)pk00, src1);
    const unsigned b2w = (unsigned)__shfl((int)pk10, src1);
    const unsigned a3w = (unsigned)__shfl((int)pk01, src1);
    const unsigned b3w = (unsigned)__shfl((int)pk11, src1);
    int4 wv;
    wv.x = (int)((quad < 2) ? a0w : b0w);
    wv.y = (int)((quad < 2) ? a1w : b1w);
    wv.z = (int)((quad < 2) ? a2w : b2w);
    wv.w = (int)((quad < 2) ? a3w : b3w);
    const short8 pf = *(const short8*)&wv;

    // ---- PV: O[q = quad*4+e][d = t*16+ln16] ------------------------------
    __builtin_amdgcn_s_setprio(1);
#pragma unroll
    for (int t = 0; t < 4; ++t)
      o[t] = __builtin_amdgcn_mfma_f32_16x16x32_bf16(pf, vf[cur][t], o[t], 0, 0, 0);
    __builtin_amdgcn_s_setprio(0);
  }

  // ---- finish row sums and normalize -------------------------------------
  s += __shfl_xor(s, 16);
  s += __shfl_xor(s, 32);
  float rinv[4];
#pragma unroll
  for (int e = 0; e < 4; ++e)
    rinv[e] = 1.f / __shfl(s, quad * 4 + e);

#pragma unroll
  for (int t = 0; t < 4; ++t)
#pragma unroll
    for (int e = 0; e < 4; ++e)
      ob[(mt * 16 + quad * 4 + e) * 68 + t * 16 + ln16] = o[t][e] * rinv[e];
  __syncthreads();
#pragma unroll
  for (int pass = 0; pass < 2; ++pass) {
    const int rr = pass * 32 + (tid >> 3), ck = tid & 7;
    const float* rp = &ob[rr * 68 + ck * 8];
    const float4 f0 = *(const float4*)&rp[0];
    const float4 f1 = *(const float4*)&rp[4];
    short8 hh;
    hh[0] = (short)f2bf(f0.x); hh[1] = (short)f2bf(f0.y);
    hh[2] = (short)f2bf(f0.z); hh[3] = (short)f2bf(f0.w);
    hh[4] = (short)f2bf(f1.x); hh[5] = (short)f2bf(f1.y);
    hh[6] = (short)f2bf(f1.z); hh[7] = (short)f2bf(f1.w);
    const size_t oo = ((size_t)(b * L_ + i0 + rr)) * 1024 + h * 64 + ck * 8;
    *(short8*)&attn_h[oo] = hh;
  }
}

// ---------------------------------------------------------------------------
extern "C" void kernel_launch(void* const* d_in, const int* in_sizes, int n_in,
                              void* d_out, int out_size, void* d_ws, size_t ws_size,
                              hipStream_t stream) {
  const float* x     = (const float*)d_in[0];
  const float* w_qkv = (const float*)d_in[1];
  const float* b_qkv = (const float*)d_in[2];
  const float* w_out = (const float*)d_in[3];
  const float* b_out = (const float*)d_in[4];
  float* out = (float*)d_out;

  const int M = B_ * L_;  // 4096

  // workspace layout (bytes), total 48 MiB:
  //   x_hi @0 (8MiB)        [dead after QKV gemm; attn_h aliases it]
  //   wqkvT @16MiB (6MiB)
  //   woutT @22MiB (2MiB)
  //   q_hi  @24MiB (8MiB)   [B*L, 1024]
  //   kT    @32MiB (8MiB)   [b][h][dg8][j2048][8d]
  //   vTile @40MiB (8MiB)   [b][jg256][d1024][8j]
  char* ws = (char*)d_ws;
  unsigned short* x_hi    = (unsigned short*)(ws + 0);
  unsigned short* wqkvT   = (unsigned short*)(ws + 16777216);
  unsigned short* woutT   = (unsigned short*)(ws + 23068672);
  unsigned short* q_hi    = (unsigned short*)(ws + 25165824);
  unsigned short* kT      = (unsigned short*)(ws + 33554432);
  unsigned short* vTile   = (unsigned short*)(ws + 41943040);
  unsigned short* attn_hi = (unsigned short*)(ws + 0);

  // 1) fused prep: x round + both weight transposes
  prep<<<8192, 256, 0, stream>>>(x, x_hi, w_qkv, wqkvT, w_out, woutT);
  // 2) fused QKV projection (r4 BK=64 structure) -> q_hi / kT / vTile
  {
    dim3 g(3072 / 128, M / 128);  // 768 blocks = 3/CU
    gemm_qkv<<<g, 256, 0, stream>>>(x_hi, wqkvT, b_qkv, q_hi, kT, vTile,
                                    3072, D_);
  }
  // 3) banded attention v3 (XCD-pinned, prefetched) -> attn_h bf16
  {
    dim3 g(L_ / 64, H_, B_);  // 1024 blocks
    attn_mfma<<<g, 256, 0, stream>>>(q_hi, kT, vTile, attn_hi);
  }
  // 4) output projection (r4 BK=64 structure) -> fp32 d_out
  {
    dim3 g(D_ / 64, M / 128);  // 512 blocks
    gemm_out<<<g, 256, 0, stream>>>(attn_hi, woutT, b_out, out, D_, D_);
  }
}